// Round 3
// baseline (177.183 us; speedup 1.0000x reference)
//
#include <hip/hip_runtime.h>
#include <hip/hip_bf16.h>

#define NN 100000
#define EE 1600000
#define ET (EE + NN)            // edges incl. self loops
#define HID 64
#define NEG 0.2f
#define NBUK 782                // ceil(NN/128) buckets of 128 dst nodes
#define SCT_TILE 4096           // edges per block in count/scatter phases
#define SH_CAP 4096             // per-bucket LDS capacity (mean 2176, sigma~47)

// ---------------- kernel 0: h1 = x@W1, ss1 = h1.a_src1, sd1 = h1.a_dst1 ----------------
__global__ __launch_bounds__(256) void k_proj(const float* __restrict__ x,
                                              const float* __restrict__ W1,
                                              const float* __restrict__ a_src1,
                                              const float* __restrict__ a_dst1,
                                              float* __restrict__ h1,
                                              float* __restrict__ ss1,
                                              float* __restrict__ sd1) {
    int wid  = threadIdx.x >> 6;
    int lane = threadIdx.x & 63;
    int n = blockIdx.x * 4 + wid;
    if (n >= NN) return;
    float h = 0.f;
#pragma unroll
    for (int k = 0; k < 5; ++k) h += x[n * 5 + k] * W1[k * HID + lane];
    h1[(size_t)n * HID + lane] = h;
    float a = h * a_src1[lane];
    float b = h * a_dst1[lane];
#pragma unroll
    for (int o = 32; o; o >>= 1) { a += __shfl_xor(a, o); b += __shfl_xor(b, o); }
    if (lane == 0) { ss1[n] = a; sd1[n] = b; }
}

// ---------------- CSR build: bucketed counting sort ----------------
// Phase A: per-bucket edge counts (LDS histogram per block)
__global__ __launch_bounds__(256) void k_bcount(const int* __restrict__ ei,
                                                int* __restrict__ bcnt) {
    __shared__ int h[NBUK];
    for (int i = threadIdx.x; i < NBUK; i += 256) h[i] = 0;
    __syncthreads();
    int base = blockIdx.x * SCT_TILE;
#pragma unroll
    for (int it = 0; it < SCT_TILE / 256; ++it) {
        int i = base + it * 256 + threadIdx.x;
        if (i < ET) {
            int d = (i < EE) ? ei[EE + i] : (i - EE);
            atomicAdd(&h[d >> 7], 1);
        }
    }
    __syncthreads();
    for (int i = threadIdx.x; i < NBUK; i += 256)
        if (h[i]) atomicAdd(&bcnt[i], h[i]);
}

// Phase B: exclusive scan of bucket counts (one block)
__global__ __launch_bounds__(1024) void k_bscan(const int* __restrict__ bcnt,
                                                int* __restrict__ bbase,
                                                int* __restrict__ bcur) {
    __shared__ int t0[1024];
    int tid = threadIdx.x;
    int v = (tid < NBUK) ? bcnt[tid] : 0;
    t0[tid] = v;
    __syncthreads();
    for (int o = 1; o < 1024; o <<= 1) {
        int t = (tid >= o) ? t0[tid - o] : 0;
        __syncthreads();
        t0[tid] += t;
        __syncthreads();
    }
    if (tid < NBUK) { int ex = t0[tid] - v; bbase[tid] = ex; bcur[tid] = ex; }
}

// Phase C: bucket-sort the tile in LDS, then flush with bucket-contiguous writes.
__global__ __launch_bounds__(256) void k_bscatter(const int* __restrict__ ei,
                                                  int* __restrict__ bcur,
                                                  unsigned* __restrict__ pairs) {
    __shared__ unsigned sp[SCT_TILE];   // bucket-sorted packed entries
    __shared__ unsigned ga[SCT_TILE];   // final global address per slot
    __shared__ int h[NBUK], loc[NBUK], cur[NBUK];
    __shared__ int tscan[256];
    int tid = threadIdx.x;
    int base = blockIdx.x * SCT_TILE;
    int tilecnt = ET - base; if (tilecnt > SCT_TILE) tilecnt = SCT_TILE;

    for (int i = tid; i < NBUK; i += 256) h[i] = 0;
    __syncthreads();
    // pass 1: bucket histogram for this tile
#pragma unroll
    for (int it = 0; it < SCT_TILE / 256; ++it) {
        int i = base + it * 256 + tid;
        if (i < ET) {
            int d = (i < EE) ? ei[EE + i] : (i - EE);
            atomicAdd(&h[d >> 7], 1);
        }
    }
    __syncthreads();
    // exclusive scan of h -> loc (4 bins per thread + block scan of totals)
    int b0 = tid * 4;
    int s0 = 0;
    if (b0 < NBUK)
        for (int k = 0; k < 4 && b0 + k < NBUK; ++k) s0 += h[b0 + k];
    tscan[tid] = s0;
    __syncthreads();
    for (int o = 1; o < 256; o <<= 1) {
        int t = (tid >= o) ? tscan[tid - o] : 0;
        __syncthreads();
        tscan[tid] += t;
        __syncthreads();
    }
    if (b0 < NBUK) {
        int run = tscan[tid] - s0;
        for (int k = 0; k < 4 && b0 + k < NBUK; ++k) {
            loc[b0 + k] = run;
            run += h[b0 + k];
        }
    }
    __syncthreads();
    // reserve global space per bucket; fold (-local_base) into cur
    for (int i = tid; i < NBUK; i += 256) {
        int c = h[i];
        cur[i] = c ? (atomicAdd(&bcur[i], c) - loc[i]) : 0;
    }
    __syncthreads();
    // pass 2: place entries bucket-contiguously in LDS, record global addresses
#pragma unroll
    for (int it = 0; it < SCT_TILE / 256; ++it) {
        int i = base + it * 256 + tid;
        if (i < ET) {
            int s, d;
            if (i < EE) { s = ei[i]; d = ei[EE + i]; }
            else        { s = i - EE; d = s; }
            int b = d >> 7;
            unsigned pk = ((unsigned)(d & 127) << 17) | (unsigned)s;
            int pos = atomicAdd(&loc[b], 1);
            sp[pos] = pk;
            ga[pos] = (unsigned)(cur[b] + pos);
        }
    }
    __syncthreads();
    // pass 3: flush (consecutive slots within a bucket -> consecutive global)
    for (int i = tid; i < tilecnt; i += 256)
        pairs[ga[i]] = sp[i];
}

// Phase D: per-bucket counting sort (in LDS), emit adj + rowptr + cnt.
// pairs and adj alias the same memory: all reads happen before the barrier.
__global__ __launch_bounds__(256) void k_bsort(const int* __restrict__ bcnt,
                                               const int* __restrict__ bbase,
                                               unsigned* __restrict__ pairs,
                                               int* __restrict__ rowptr,
                                               int* __restrict__ cntd) {
    __shared__ unsigned sp[SH_CAP];
    __shared__ int hist[128], sc[128], cur2[128];
    int b = blockIdx.x;
    int cnt = bcnt[b];
    if (cnt > SH_CAP) cnt = SH_CAP;   // statistically impossible; memory-safety only
    int base = bbase[b];
    int tid = threadIdx.x;
    if (tid < 128) hist[tid] = 0;
    __syncthreads();
    for (int i = tid; i < cnt; i += 256) {
        unsigned p = pairs[base + i];
        sp[i] = p;
        atomicAdd(&hist[p >> 17], 1);
    }
    __syncthreads();
    if (tid < 128) sc[tid] = hist[tid];
    __syncthreads();
    for (int o = 1; o < 128; o <<= 1) {
        int t = (tid < 128 && tid >= o) ? sc[tid - o] : 0;
        __syncthreads();
        if (tid < 128) sc[tid] += t;
        __syncthreads();
    }
    int nbase = b << 7;
    if (tid < 128 && nbase + tid < NN) {
        int ex = sc[tid] - hist[tid];
        rowptr[nbase + tid] = base + ex;
        cntd[nbase + tid]   = hist[tid];
        cur2[tid] = ex;
    }
    __syncthreads();
    int* adj = (int*)pairs;
    for (int i = tid; i < cnt; i += 256) {
        unsigned p = sp[i];
        int ld = p >> 17;
        int pos = atomicAdd(&cur2[ld], 1);
        adj[base + pos] = (int)(p & 0x1FFFF);
    }
}

// ---------------- layer 1 softmax-aggregate (+ fused bias/ReLU/W2) ----------------
__global__ __launch_bounds__(256) void k_agg1(const int* __restrict__ rowptr,
                                              const int* __restrict__ cntd,
                                              const int* __restrict__ adj,
                                              const float* __restrict__ ss1,
                                              const float* __restrict__ sd1,
                                              const float* __restrict__ h1,
                                              const float* __restrict__ b1,
                                              const float* __restrict__ W2,
                                              float* __restrict__ h2) {
    __shared__ float lw[4][64];
    __shared__ int   lsrc[4][64];
    int wid  = threadIdx.x >> 6;
    int lane = threadIdx.x & 63;
    int n = blockIdx.x * 4 + wid;
    if (n >= NN) return;
    int off = rowptr[n], deg = cntd[n];
    float sdn = sd1[n];

    if (deg <= 64) {
        // ---- fast path ----
        int s = 0; float e = -1e30f;
        if (lane < deg) {
            s = adj[off + lane];
            float t = ss1[s] + sdn;
            e = t > 0.f ? t : NEG * t;
        }
        float m = e;
#pragma unroll
        for (int o = 32; o; o >>= 1) m = fmaxf(m, __shfl_xor(m, o));
        float p = (lane < deg) ? __expf(e - m) : 0.f;
        float ds = p;
#pragma unroll
        for (int o = 32; o; o >>= 1) ds += __shfl_xor(ds, o);
        float w = p * (1.0f / ds);
        lw[wid][lane] = w;
        lsrc[wid][lane] = s;
        // subgroup gather: 4 subgroups of 16 lanes; subgroup g takes edges t%4==g,
        // lane covers features c*4..c*4+3 via float4 -> 4 rows in flight per load round.
        int g = lane >> 4, c = lane & 15;
        float a0x = 0.f, a0y = 0.f, a0z = 0.f, a0w = 0.f;
        float a1x = 0.f, a1y = 0.f, a1z = 0.f, a1w = 0.f;
        for (int tb = 0; tb < deg; tb += 8) {
            int t0 = tb + g, t1 = tb + g + 4;
            if (t0 < deg) {
                float w0 = lw[wid][t0];
                const float4 v0 = *(const float4*)(h1 + (size_t)lsrc[wid][t0] * HID + c * 4);
                a0x += w0 * v0.x; a0y += w0 * v0.y; a0z += w0 * v0.z; a0w += w0 * v0.w;
            }
            if (t1 < deg) {
                float w1 = lw[wid][t1];
                const float4 v1 = *(const float4*)(h1 + (size_t)lsrc[wid][t1] * HID + c * 4);
                a1x += w1 * v1.x; a1y += w1 * v1.y; a1z += w1 * v1.z; a1w += w1 * v1.w;
            }
        }
        float ax = a0x + a1x, ay = a0y + a1y, az = a0z + a1z, aw = a0w + a1w;
#pragma unroll
        for (int o = 16; o <= 32; o <<= 1) {
            ax += __shfl_xor(ax, o); ay += __shfl_xor(ay, o);
            az += __shfl_xor(az, o); aw += __shfl_xor(aw, o);
        }
        // epilogue: +b1, ReLU, dot with W2 (4 features per lane)
        const float4 b4 = *(const float4*)(b1 + c * 4);
        const float4 W4 = *(const float4*)(W2 + c * 4);
        float vx = fmaxf(ax + b4.x, 0.f);
        float vy = fmaxf(ay + b4.y, 0.f);
        float vz = fmaxf(az + b4.z, 0.f);
        float vw = fmaxf(aw + b4.w, 0.f);
        float p2 = vx * W4.x + vy * W4.y + vz * W4.z + vw * W4.w;
#pragma unroll
        for (int o = 1; o <= 8; o <<= 1) p2 += __shfl_xor(p2, o);
        if (lane == 0) h2[n] = p2;
    } else {
        // ---- generic chunked 3-pass path (rare) ----
        float acc = 0.f;
        float m = -1e30f;
        for (int j0 = 0; j0 < deg; j0 += 64) {
            int j = j0 + lane;
            if (j < deg) {
                int s = adj[off + j];
                float e = ss1[s] + sdn;
                e = e > 0.f ? e : NEG * e;
                m = fmaxf(m, e);
            }
        }
#pragma unroll
        for (int o = 32; o; o >>= 1) m = fmaxf(m, __shfl_xor(m, o));
        float dsum = 0.f;
        for (int j0 = 0; j0 < deg; j0 += 64) {
            int j = j0 + lane;
            if (j < deg) {
                int s = adj[off + j];
                float e = ss1[s] + sdn;
                e = e > 0.f ? e : NEG * e;
                dsum += __expf(e - m);
            }
        }
#pragma unroll
        for (int o = 32; o; o >>= 1) dsum += __shfl_xor(dsum, o);
        float inv = 1.0f / dsum;
        for (int j0 = 0; j0 < deg; j0 += 64) {
            int j = j0 + lane;
            float w = 0.f; int s = 0;
            if (j < deg) {
                s = adj[off + j];
                float e = ss1[s] + sdn;
                e = e > 0.f ? e : NEG * e;
                w = __expf(e - m) * inv;
            }
            int lim = deg - j0; if (lim > 64) lim = 64;
            for (int t = 0; t < lim; ++t) {
                float cc = __shfl(w, t);
                int  sj = __shfl(s, t);
                acc += cc * h1[(size_t)sj * HID + lane];
            }
        }
        float v = acc + b1[lane];
        v = fmaxf(v, 0.f);
        float p2 = v * W2[lane];
#pragma unroll
        for (int o = 32; o; o >>= 1) p2 += __shfl_xor(p2, o);
        if (lane == 0) h2[n] = p2;
    }
}

// ---------------- layer 2 softmax-aggregate (scalar features, single pass) ----------------
__global__ __launch_bounds__(256) void k_agg2(const int* __restrict__ rowptr,
                                              const int* __restrict__ cntd,
                                              const int* __restrict__ adj,
                                              const float* __restrict__ h2,
                                              const float* __restrict__ as2,
                                              const float* __restrict__ ad2,
                                              const float* __restrict__ b2,
                                              float* __restrict__ out) {
    int wid  = threadIdx.x >> 6;
    int lane = threadIdx.x & 63;
    int n = blockIdx.x * 4 + wid;
    if (n >= NN) return;
    int off = rowptr[n], deg = cntd[n];
    float as2v = as2[0];
    float sdn = h2[n] * ad2[0];

    if (deg <= 64) {
        float hv = 0.f, e = -1e30f;
        if (lane < deg) {
            int s = adj[off + lane];
            hv = h2[s];
            float t = hv * as2v + sdn;
            e = t > 0.f ? t : NEG * t;
        }
        float m = e;
#pragma unroll
        for (int o = 32; o; o >>= 1) m = fmaxf(m, __shfl_xor(m, o));
        float p = (lane < deg) ? __expf(e - m) : 0.f;
        float ds = p, ns = p * hv;
#pragma unroll
        for (int o = 32; o; o >>= 1) { ds += __shfl_xor(ds, o); ns += __shfl_xor(ns, o); }
        if (lane == 0) out[n] = ns / ds + b2[0];
    } else {
        float m = -1e30f;
        for (int j0 = 0; j0 < deg; j0 += 64) {
            int j = j0 + lane;
            if (j < deg) {
                int s = adj[off + j];
                float e = h2[s] * as2v + sdn;
                e = e > 0.f ? e : NEG * e;
                m = fmaxf(m, e);
            }
        }
#pragma unroll
        for (int o = 32; o; o >>= 1) m = fmaxf(m, __shfl_xor(m, o));
        float dsum = 0.f, nsum = 0.f;
        for (int j0 = 0; j0 < deg; j0 += 64) {
            int j = j0 + lane;
            if (j < deg) {
                int s = adj[off + j];
                float hv = h2[s];
                float e = hv * as2v + sdn;
                e = e > 0.f ? e : NEG * e;
                float ex = __expf(e - m);
                dsum += ex;
                nsum += ex * hv;
            }
        }
#pragma unroll
        for (int o = 32; o; o >>= 1) { dsum += __shfl_xor(dsum, o); nsum += __shfl_xor(nsum, o); }
        if (lane == 0) out[n] = nsum / dsum + b2[0];
    }
}

extern "C" void kernel_launch(void* const* d_in, const int* in_sizes, int n_in,
                              void* d_out, int out_size, void* d_ws, size_t ws_size,
                              hipStream_t stream) {
    const float* x      = (const float*)d_in[0];
    const int*   ei     = (const int*)d_in[1];
    const float* W1     = (const float*)d_in[2];
    const float* a_src1 = (const float*)d_in[3];
    const float* a_dst1 = (const float*)d_in[4];
    const float* b1     = (const float*)d_in[5];
    const float* W2     = (const float*)d_in[6];
    const float* as2    = (const float*)d_in[7];
    const float* ad2    = (const float*)d_in[8];
    const float* b2     = (const float*)d_in[9];
    float* out = (float*)d_out;

    // workspace layout (all 4-byte elements)
    float* h1   = (float*)d_ws;                // N*64
    float* ss1  = h1 + (size_t)NN * HID;       // N
    float* sd1  = ss1 + NN;                    // N
    float* h2   = sd1 + NN;                    // N
    int* rowptr = (int*)(h2 + NN);             // N
    int* cntd   = rowptr + NN;                 // N
    int* bcnt   = cntd + NN;                   // 1024
    int* bbase  = bcnt + 1024;                 // 1024
    int* bcur   = bbase + 1024;                // 1024
    unsigned* pairs = (unsigned*)(bcur + 1024);// ET (reused as adj)
    int* adj    = (int*)pairs;

    const int NSCT = (ET + SCT_TILE - 1) / SCT_TILE;   // 416

    hipMemsetAsync(bcnt, 0, 1024 * sizeof(int), stream);

    k_proj<<<(NN + 3) / 4, 256, 0, stream>>>(x, W1, a_src1, a_dst1, h1, ss1, sd1);
    k_bcount<<<NSCT, 256, 0, stream>>>(ei, bcnt);
    k_bscan<<<1, 1024, 0, stream>>>(bcnt, bbase, bcur);
    k_bscatter<<<NSCT, 256, 0, stream>>>(ei, bcur, pairs);
    k_bsort<<<NBUK, 256, 0, stream>>>(bcnt, bbase, pairs, rowptr, cntd);
    k_agg1<<<(NN + 3) / 4, 256, 0, stream>>>(rowptr, cntd, adj, ss1, sd1, h1, b1, W2, h2);
    k_agg2<<<(NN + 3) / 4, 256, 0, stream>>>(rowptr, cntd, adj, h2, as2, ad2, b2, out);
}

// Round 4
// 150.673 us; speedup vs baseline: 1.1759x; 1.1759x over previous
//
#include <hip/hip_runtime.h>
#include <hip/hip_bf16.h>

#define NN 100000
#define EE 1600000
#define ET (EE + NN)            // edges incl. self loops
#define HID 64
#define NEG 0.2f
#define NBUK 782                // ceil(NN/128) buckets of 128 dst nodes
#define SCT_TILE 4096           // edges per block in scatter phase
#define BUKCAP 4096             // padded per-bucket capacity (mean 2176, sigma~47)
#define SH_CAP 4096

typedef unsigned short ushort_t;
#define BF(u) __uint_as_float((unsigned)(u) << 16)

// ---------------- kernel 0: h1 = x@W1 (bf16), ss1 = h1.a_src1, sd1 = h1.a_dst1 ----------------
__global__ __launch_bounds__(256) void k_proj(const float* __restrict__ x,
                                              const float* __restrict__ W1,
                                              const float* __restrict__ a_src1,
                                              const float* __restrict__ a_dst1,
                                              ushort_t* __restrict__ h1b,
                                              float* __restrict__ ss1,
                                              float* __restrict__ sd1) {
    int wid  = threadIdx.x >> 6;
    int lane = threadIdx.x & 63;
    int n = blockIdx.x * 4 + wid;
    if (n >= NN) return;
    float h = 0.f;
#pragma unroll
    for (int k = 0; k < 5; ++k) h += x[n * 5 + k] * W1[k * HID + lane];
    // round-to-nearest-even bf16
    unsigned u = __float_as_uint(h);
    unsigned r = (u + 0x7FFFu + ((u >> 16) & 1u)) >> 16;
    h1b[(size_t)n * HID + lane] = (ushort_t)r;
    float hq = BF(r);                 // scores computed from the QUANTIZED h for consistency
    float a = hq * a_src1[lane];
    float b = hq * a_dst1[lane];
#pragma unroll
    for (int o = 32; o; o >>= 1) { a += __shfl_xor(a, o); b += __shfl_xor(b, o); }
    if (lane == 0) { ss1[n] = a; sd1[n] = b; }
}

// ---------------- CSR build ----------------
// Phase C: bucket-sort each tile in LDS, reserve padded bucket regions, flush contiguously.
__global__ __launch_bounds__(256) void k_bscatter(const int* __restrict__ ei,
                                                  int* __restrict__ bcur,
                                                  unsigned* __restrict__ pairs) {
    __shared__ unsigned sp[SCT_TILE];   // bucket-sorted packed entries
    __shared__ unsigned ga[SCT_TILE];   // final global address per slot
    __shared__ int h[NBUK], loc[NBUK], cur[NBUK];
    __shared__ int tscan[256];
    int tid = threadIdx.x;
    int base = blockIdx.x * SCT_TILE;
    int tilecnt = ET - base; if (tilecnt > SCT_TILE) tilecnt = SCT_TILE;

    for (int i = tid; i < NBUK; i += 256) h[i] = 0;
    __syncthreads();
    // pass 1: bucket histogram for this tile
#pragma unroll
    for (int it = 0; it < SCT_TILE / 256; ++it) {
        int i = base + it * 256 + tid;
        if (i < ET) {
            int d = (i < EE) ? ei[EE + i] : (i - EE);
            atomicAdd(&h[d >> 7], 1);
        }
    }
    __syncthreads();
    // exclusive scan of h -> loc (4 bins per thread + block scan of totals)
    int b0 = tid * 4;
    int s0 = 0;
    if (b0 < NBUK)
        for (int k = 0; k < 4 && b0 + k < NBUK; ++k) s0 += h[b0 + k];
    tscan[tid] = s0;
    __syncthreads();
    for (int o = 1; o < 256; o <<= 1) {
        int t = (tid >= o) ? tscan[tid - o] : 0;
        __syncthreads();
        tscan[tid] += t;
        __syncthreads();
    }
    if (b0 < NBUK) {
        int run = tscan[tid] - s0;
        for (int k = 0; k < 4 && b0 + k < NBUK; ++k) {
            loc[b0 + k] = run;
            run += h[b0 + k];
        }
    }
    __syncthreads();
    // reserve space in padded bucket region; fold (region base - local base) into cur
    for (int i = tid; i < NBUK; i += 256) {
        int c = h[i];
        cur[i] = c ? (atomicAdd(&bcur[i], c) + i * BUKCAP - loc[i]) : 0;
    }
    __syncthreads();
    // pass 2: place entries bucket-contiguously in LDS, record global addresses
#pragma unroll
    for (int it = 0; it < SCT_TILE / 256; ++it) {
        int i = base + it * 256 + tid;
        if (i < ET) {
            int s, d;
            if (i < EE) { s = ei[i]; d = ei[EE + i]; }
            else        { s = i - EE; d = s; }
            int b = d >> 7;
            unsigned pk = ((unsigned)(d & 127) << 17) | (unsigned)s;
            int pos = atomicAdd(&loc[b], 1);
            sp[pos] = pk;
            ga[pos] = (unsigned)(cur[b] + pos);
        }
    }
    __syncthreads();
    // pass 3: flush (consecutive slots within a bucket -> consecutive global)
    for (int i = tid; i < tilecnt; i += 256)
        pairs[ga[i]] = sp[i];
}

// Phase D: per-bucket counting sort (in LDS), emit adj + rowptr + cnt.
// pairs and adj alias: all reads complete before the barrier preceding writes.
__global__ __launch_bounds__(256) void k_bsort(const int* __restrict__ bcur,
                                               unsigned* __restrict__ pairs,
                                               int* __restrict__ rowptr,
                                               int* __restrict__ cntd) {
    __shared__ unsigned sp[SH_CAP];
    __shared__ int hist[128], sc[128], cur2[128];
    int b = blockIdx.x;
    int cnt = bcur[b];
    if (cnt > SH_CAP) cnt = SH_CAP;   // statistically impossible; memory-safety only
    int base = b * BUKCAP;
    int tid = threadIdx.x;
    if (tid < 128) hist[tid] = 0;
    __syncthreads();
    for (int i = tid; i < cnt; i += 256) {
        unsigned p = pairs[base + i];
        sp[i] = p;
        atomicAdd(&hist[p >> 17], 1);
    }
    __syncthreads();
    if (tid < 128) sc[tid] = hist[tid];
    __syncthreads();
    for (int o = 1; o < 128; o <<= 1) {
        int t = (tid < 128 && tid >= o) ? sc[tid - o] : 0;
        __syncthreads();
        if (tid < 128) sc[tid] += t;
        __syncthreads();
    }
    int nbase = b << 7;
    if (tid < 128 && nbase + tid < NN) {
        int ex = sc[tid] - hist[tid];
        rowptr[nbase + tid] = base + ex;
        cntd[nbase + tid]   = hist[tid];
        cur2[tid] = ex;
    }
    __syncthreads();
    int* adj = (int*)pairs;
    for (int i = tid; i < cnt; i += 256) {
        unsigned p = sp[i];
        int ld = p >> 17;
        int pos = atomicAdd(&cur2[ld], 1);
        adj[base + pos] = (int)(p & 0x1FFFF);
    }
}

// ---------------- layer 1 softmax-aggregate (+ fused bias/ReLU/W2) ----------------
__global__ __launch_bounds__(256) void k_agg1(const int* __restrict__ rowptr,
                                              const int* __restrict__ cntd,
                                              const int* __restrict__ adj,
                                              const float* __restrict__ ss1,
                                              const float* __restrict__ sd1,
                                              const ushort_t* __restrict__ h1b,
                                              const float* __restrict__ b1,
                                              const float* __restrict__ W2,
                                              float* __restrict__ h2) {
    __shared__ float lw[4][64];
    __shared__ int   lsrc[4][64];
    int wid  = threadIdx.x >> 6;
    int lane = threadIdx.x & 63;
    int n = blockIdx.x * 4 + wid;
    if (n >= NN) return;
    int off = rowptr[n], deg = cntd[n];
    float sdn = sd1[n];

    if (deg <= 64) {
        // ---- fast path ----
        int s = 0; float e = -1e30f;
        if (lane < deg) {
            s = adj[off + lane];
            float t = ss1[s] + sdn;
            e = t > 0.f ? t : NEG * t;
        }
        float m = e;
#pragma unroll
        for (int o = 32; o; o >>= 1) m = fmaxf(m, __shfl_xor(m, o));
        float p = (lane < deg) ? __expf(e - m) : 0.f;
        float ds = p;
#pragma unroll
        for (int o = 32; o; o >>= 1) ds += __shfl_xor(ds, o);
        float w = p * (1.0f / ds);
        lw[wid][lane] = w;
        lsrc[wid][lane] = s;
        // subgroup gather: 4 subgroups x 16 lanes; lane covers 4 bf16 features (8B load),
        // 2-way unrolled -> up to 8 independent 128B rows in flight per wave.
        int g = lane >> 4, c = lane & 15;
        float a0x = 0.f, a0y = 0.f, a0z = 0.f, a0w = 0.f;
        float a1x = 0.f, a1y = 0.f, a1z = 0.f, a1w = 0.f;
        for (int tb = 0; tb < deg; tb += 8) {
            int t0 = tb + g, t1 = tb + g + 4;
            if (t0 < deg) {
                float w0 = lw[wid][t0];
                const ushort4 v0 = *(const ushort4*)(h1b + (size_t)lsrc[wid][t0] * HID + (c << 2));
                a0x += w0 * BF(v0.x); a0y += w0 * BF(v0.y);
                a0z += w0 * BF(v0.z); a0w += w0 * BF(v0.w);
            }
            if (t1 < deg) {
                float w1 = lw[wid][t1];
                const ushort4 v1 = *(const ushort4*)(h1b + (size_t)lsrc[wid][t1] * HID + (c << 2));
                a1x += w1 * BF(v1.x); a1y += w1 * BF(v1.y);
                a1z += w1 * BF(v1.z); a1w += w1 * BF(v1.w);
            }
        }
        float ax = a0x + a1x, ay = a0y + a1y, az = a0z + a1z, aw = a0w + a1w;
#pragma unroll
        for (int o = 16; o <= 32; o <<= 1) {
            ax += __shfl_xor(ax, o); ay += __shfl_xor(ay, o);
            az += __shfl_xor(az, o); aw += __shfl_xor(aw, o);
        }
        // epilogue: +b1, ReLU, dot with W2 (4 features per lane)
        const float4 b4 = *(const float4*)(b1 + c * 4);
        const float4 W4 = *(const float4*)(W2 + c * 4);
        float vx = fmaxf(ax + b4.x, 0.f);
        float vy = fmaxf(ay + b4.y, 0.f);
        float vz = fmaxf(az + b4.z, 0.f);
        float vw = fmaxf(aw + b4.w, 0.f);
        float p2 = vx * W4.x + vy * W4.y + vz * W4.z + vw * W4.w;
#pragma unroll
        for (int o = 1; o <= 8; o <<= 1) p2 += __shfl_xor(p2, o);
        if (lane == 0) h2[n] = p2;
    } else {
        // ---- generic chunked 3-pass path (rare) ----
        float acc = 0.f;
        float m = -1e30f;
        for (int j0 = 0; j0 < deg; j0 += 64) {
            int j = j0 + lane;
            if (j < deg) {
                int s = adj[off + j];
                float e = ss1[s] + sdn;
                e = e > 0.f ? e : NEG * e;
                m = fmaxf(m, e);
            }
        }
#pragma unroll
        for (int o = 32; o; o >>= 1) m = fmaxf(m, __shfl_xor(m, o));
        float dsum = 0.f;
        for (int j0 = 0; j0 < deg; j0 += 64) {
            int j = j0 + lane;
            if (j < deg) {
                int s = adj[off + j];
                float e = ss1[s] + sdn;
                e = e > 0.f ? e : NEG * e;
                dsum += __expf(e - m);
            }
        }
#pragma unroll
        for (int o = 32; o; o >>= 1) dsum += __shfl_xor(dsum, o);
        float inv = 1.0f / dsum;
        for (int j0 = 0; j0 < deg; j0 += 64) {
            int j = j0 + lane;
            float w = 0.f; int s = 0;
            if (j < deg) {
                s = adj[off + j];
                float e = ss1[s] + sdn;
                e = e > 0.f ? e : NEG * e;
                w = __expf(e - m) * inv;
            }
            int lim = deg - j0; if (lim > 64) lim = 64;
            for (int t = 0; t < lim; ++t) {
                float cc = __shfl(w, t);
                int  sj = __shfl(s, t);
                acc += cc * BF(h1b[(size_t)sj * HID + lane]);
            }
        }
        float v = acc + b1[lane];
        v = fmaxf(v, 0.f);
        float p2 = v * W2[lane];
#pragma unroll
        for (int o = 32; o; o >>= 1) p2 += __shfl_xor(p2, o);
        if (lane == 0) h2[n] = p2;
    }
}

// ---------------- layer 2 softmax-aggregate (scalar features, single pass) ----------------
__global__ __launch_bounds__(256) void k_agg2(const int* __restrict__ rowptr,
                                              const int* __restrict__ cntd,
                                              const int* __restrict__ adj,
                                              const float* __restrict__ h2,
                                              const float* __restrict__ as2,
                                              const float* __restrict__ ad2,
                                              const float* __restrict__ b2,
                                              float* __restrict__ out) {
    int wid  = threadIdx.x >> 6;
    int lane = threadIdx.x & 63;
    int n = blockIdx.x * 4 + wid;
    if (n >= NN) return;
    int off = rowptr[n], deg = cntd[n];
    float as2v = as2[0];
    float sdn = h2[n] * ad2[0];

    if (deg <= 64) {
        float hv = 0.f, e = -1e30f;
        if (lane < deg) {
            int s = adj[off + lane];
            hv = h2[s];
            float t = hv * as2v + sdn;
            e = t > 0.f ? t : NEG * t;
        }
        float m = e;
#pragma unroll
        for (int o = 32; o; o >>= 1) m = fmaxf(m, __shfl_xor(m, o));
        float p = (lane < deg) ? __expf(e - m) : 0.f;
        float ds = p, ns = p * hv;
#pragma unroll
        for (int o = 32; o; o >>= 1) { ds += __shfl_xor(ds, o); ns += __shfl_xor(ns, o); }
        if (lane == 0) out[n] = ns / ds + b2[0];
    } else {
        float m = -1e30f;
        for (int j0 = 0; j0 < deg; j0 += 64) {
            int j = j0 + lane;
            if (j < deg) {
                int s = adj[off + j];
                float e = h2[s] * as2v + sdn;
                e = e > 0.f ? e : NEG * e;
                m = fmaxf(m, e);
            }
        }
#pragma unroll
        for (int o = 32; o; o >>= 1) m = fmaxf(m, __shfl_xor(m, o));
        float dsum = 0.f, nsum = 0.f;
        for (int j0 = 0; j0 < deg; j0 += 64) {
            int j = j0 + lane;
            if (j < deg) {
                int s = adj[off + j];
                float hv = h2[s];
                float e = hv * as2v + sdn;
                e = e > 0.f ? e : NEG * e;
                float ex = __expf(e - m);
                dsum += ex;
                nsum += ex * hv;
            }
        }
#pragma unroll
        for (int o = 32; o; o >>= 1) { dsum += __shfl_xor(dsum, o); nsum += __shfl_xor(nsum, o); }
        if (lane == 0) out[n] = nsum / dsum + b2[0];
    }
}

extern "C" void kernel_launch(void* const* d_in, const int* in_sizes, int n_in,
                              void* d_out, int out_size, void* d_ws, size_t ws_size,
                              hipStream_t stream) {
    const float* x      = (const float*)d_in[0];
    const int*   ei     = (const int*)d_in[1];
    const float* W1     = (const float*)d_in[2];
    const float* a_src1 = (const float*)d_in[3];
    const float* a_dst1 = (const float*)d_in[4];
    const float* b1     = (const float*)d_in[5];
    const float* W2     = (const float*)d_in[6];
    const float* as2    = (const float*)d_in[7];
    const float* ad2    = (const float*)d_in[8];
    const float* b2     = (const float*)d_in[9];
    float* out = (float*)d_out;

    // workspace layout
    ushort_t* h1b = (ushort_t*)d_ws;                    // N*64 bf16 = 12.8MB
    float* ss1  = (float*)(h1b + (size_t)NN * HID);     // N
    float* sd1  = ss1 + NN;                             // N
    float* h2   = sd1 + NN;                             // N
    int* rowptr = (int*)(h2 + NN);                      // N
    int* cntd   = rowptr + NN;                          // N
    int* bcur   = cntd + NN;                            // 1024
    unsigned* pairs = (unsigned*)(bcur + 1024);         // (NBUK+1)*BUKCAP (reused as adj)
    int* adj    = (int*)pairs;

    const int NSCT = (ET + SCT_TILE - 1) / SCT_TILE;    // 416

    hipMemsetAsync(bcur, 0, 1024 * sizeof(int), stream);

    k_proj<<<(NN + 3) / 4, 256, 0, stream>>>(x, W1, a_src1, a_dst1, h1b, ss1, sd1);
    k_bscatter<<<NSCT, 256, 0, stream>>>(ei, bcur, pairs);
    k_bsort<<<NBUK, 256, 0, stream>>>(bcur, pairs, rowptr, cntd);
    k_agg1<<<(NN + 3) / 4, 256, 0, stream>>>(rowptr, cntd, adj, ss1, sd1, h1b, b1, W2, h2);
    k_agg2<<<(NN + 3) / 4, 256, 0, stream>>>(rowptr, cntd, adj, h2, as2, ad2, b2, out);
}

// Round 5
// 142.867 us; speedup vs baseline: 1.2402x; 1.0546x over previous
//
#include <hip/hip_runtime.h>
#include <hip/hip_bf16.h>

#define NN 100000
#define EE 1600000
#define ET (EE + NN)            // edges incl. self loops
#define HID 64
#define NEG 0.2f
#define NBUK 782                // ceil(NN/128) buckets of 128 dst nodes
#define SCT_TILE 4096           // edges per block in scatter phase
#define BUKCAP 4096             // padded per-bucket capacity (mean 2176, sigma~47)
#define SH_CAP 4096

typedef unsigned short ushort_t;
#define BF(u)   __uint_as_float((unsigned)(u) << 16)
#define BFLO(u) __uint_as_float((unsigned)(u) << 16)
#define BFHI(u) __uint_as_float((unsigned)(u) & 0xFFFF0000u)

// ---------------- kernel 0: h1 = x@W1 (bf16), ss1 = h1.a_src1, sd1 = h1.a_dst1 ----------------
__global__ __launch_bounds__(256) void k_proj(const float* __restrict__ x,
                                              const float* __restrict__ W1,
                                              const float* __restrict__ a_src1,
                                              const float* __restrict__ a_dst1,
                                              ushort_t* __restrict__ h1b,
                                              float* __restrict__ ss1,
                                              float* __restrict__ sd1) {
    int wid  = threadIdx.x >> 6;
    int lane = threadIdx.x & 63;
    int n = blockIdx.x * 4 + wid;
    if (n >= NN) return;
    float h = 0.f;
#pragma unroll
    for (int k = 0; k < 5; ++k) h += x[n * 5 + k] * W1[k * HID + lane];
    // round-to-nearest-even bf16
    unsigned u = __float_as_uint(h);
    unsigned r = (u + 0x7FFFu + ((u >> 16) & 1u)) >> 16;
    h1b[(size_t)n * HID + lane] = (ushort_t)r;
    float hq = BF(r);                 // scores from QUANTIZED h for consistency
    float a = hq * a_src1[lane];
    float b = hq * a_dst1[lane];
#pragma unroll
    for (int o = 32; o; o >>= 1) { a += __shfl_xor(a, o); b += __shfl_xor(b, o); }
    if (lane == 0) { ss1[n] = a; sd1[n] = b; }
}

// ---------------- CSR build ----------------
// Phase C: bucket-sort each tile in LDS, reserve padded bucket regions, flush contiguously.
// Edge list is read exactly once; (s,d) kept in registers across both passes.
__global__ __launch_bounds__(256) void k_bscatter(const int* __restrict__ ei,
                                                  int* __restrict__ bcur,
                                                  unsigned* __restrict__ pairs) {
    __shared__ unsigned sp[SCT_TILE];   // bucket-sorted packed entries
    __shared__ unsigned ga[SCT_TILE];   // final global address per slot
    __shared__ int h[NBUK], loc[NBUK], cur[NBUK];
    __shared__ int wsum[4];
    int tid = threadIdx.x;
    int wid = tid >> 6, lane = tid & 63;
    int base = blockIdx.x * SCT_TILE;
    int tilecnt = ET - base; if (tilecnt > SCT_TILE) tilecnt = SCT_TILE;

    for (int i = tid; i < NBUK; i += 256) h[i] = 0;
    __syncthreads();
    // single read pass: stash (s,d) in registers, build bucket histogram
    int sreg[SCT_TILE / 256], dreg[SCT_TILE / 256];
#pragma unroll
    for (int it = 0; it < SCT_TILE / 256; ++it) {
        int i = base + it * 256 + tid;
        if (i < ET) {
            int s, d;
            if (i < EE) { s = ei[i]; d = ei[EE + i]; }
            else        { s = i - EE; d = s; }
            sreg[it] = s; dreg[it] = d;
            atomicAdd(&h[d >> 7], 1);
        } else dreg[it] = -1;
    }
    __syncthreads();
    // exclusive scan of h -> loc: 4 bins/thread, wave shuffle scan, cross-wave fixup
    int b0 = tid * 4;
    int s0 = 0;
    if (b0 < NBUK)
        for (int k = 0; k < 4 && b0 + k < NBUK; ++k) s0 += h[b0 + k];
    int incl = s0;
#pragma unroll
    for (int o = 1; o < 64; o <<= 1) {
        int t = __shfl(incl, (lane - o) & 63);
        if (lane >= o) incl += t;
    }
    if (lane == 63) wsum[wid] = incl;
    __syncthreads();
    int wpref = 0;
    for (int w = 0; w < wid; ++w) wpref += wsum[w];
    if (b0 < NBUK) {
        int run = wpref + incl - s0;   // exclusive prefix
        for (int k = 0; k < 4 && b0 + k < NBUK; ++k) {
            loc[b0 + k] = run;
            run += h[b0 + k];
        }
    }
    __syncthreads();
    // reserve space in padded bucket region; fold (region base - local base) into cur
    for (int i = tid; i < NBUK; i += 256) {
        int c = h[i];
        cur[i] = c ? (atomicAdd(&bcur[i], c) + i * BUKCAP - loc[i]) : 0;
    }
    __syncthreads();
    // placement pass (from registers), record global addresses
#pragma unroll
    for (int it = 0; it < SCT_TILE / 256; ++it) {
        if (dreg[it] >= 0) {
            int s = sreg[it], d = dreg[it];
            int b = d >> 7;
            unsigned pk = ((unsigned)(d & 127) << 17) | (unsigned)s;
            int pos = atomicAdd(&loc[b], 1);
            sp[pos] = pk;
            ga[pos] = (unsigned)(cur[b] + pos);
        }
    }
    __syncthreads();
    // flush (consecutive slots within a bucket -> consecutive global)
    for (int i = tid; i < tilecnt; i += 256)
        pairs[ga[i]] = sp[i];
}

// Phase D: per-bucket counting sort (in LDS), emit adj + rowptr + cnt.
// pairs and adj alias: all reads complete before the barrier preceding writes.
__global__ __launch_bounds__(256) void k_bsort(const int* __restrict__ bcur,
                                               unsigned* __restrict__ pairs,
                                               int* __restrict__ rowptr,
                                               int* __restrict__ cntd) {
    __shared__ unsigned sp[SH_CAP];
    __shared__ int hist[128], sc[128], cur2[128];
    int b = blockIdx.x;
    int cnt = bcur[b];
    if (cnt > SH_CAP) cnt = SH_CAP;   // statistically impossible; memory-safety only
    int base = b * BUKCAP;
    int tid = threadIdx.x;
    if (tid < 128) hist[tid] = 0;
    __syncthreads();
    for (int i = tid; i < cnt; i += 256) {
        unsigned p = pairs[base + i];
        sp[i] = p;
        atomicAdd(&hist[p >> 17], 1);
    }
    __syncthreads();
    // 128-bin exclusive scan on one wave (2 bins per lane, shuffle scan)
    if (tid < 64) {
        int v0 = hist[2 * tid], v1 = hist[2 * tid + 1];
        int s = v0 + v1;
#pragma unroll
        for (int o = 1; o < 64; o <<= 1) {
            int t = __shfl(s, (tid - o) & 63);
            if (tid >= o) s += t;
        }
        int excl = s - v0 - v1;
        sc[2 * tid] = excl;
        sc[2 * tid + 1] = excl + v0;
    }
    __syncthreads();
    int nbase = b << 7;
    if (tid < 128 && nbase + tid < NN) {
        rowptr[nbase + tid] = base + sc[tid];
        cntd[nbase + tid]   = hist[tid];
        cur2[tid] = sc[tid];
    }
    __syncthreads();
    int* adj = (int*)pairs;
    for (int i = tid; i < cnt; i += 256) {
        unsigned p = sp[i];
        int ld = p >> 17;
        int pos = atomicAdd(&cur2[ld], 1);
        adj[base + pos] = (int)(p & 0x1FFFF);
    }
}

// ---------------- layer 1 softmax-aggregate (+ fused bias/ReLU/W2) ----------------
__global__ __launch_bounds__(256) void k_agg1(const int* __restrict__ rowptr,
                                              const int* __restrict__ cntd,
                                              const int* __restrict__ adj,
                                              const float* __restrict__ ss1,
                                              const float* __restrict__ sd1,
                                              const ushort_t* __restrict__ h1b,
                                              const float* __restrict__ b1,
                                              const float* __restrict__ W2,
                                              float* __restrict__ h2) {
    __shared__ float lw[4][64];
    __shared__ int   lsrc[4][64];
    int wid  = threadIdx.x >> 6;
    int lane = threadIdx.x & 63;
    int n = blockIdx.x * 4 + wid;
    if (n >= NN) return;
    int off = rowptr[n], deg = cntd[n];
    float sdn = sd1[n];

    if (deg <= 64) {
        // ---- fast path ----
        int s = 0; float e = -1e30f;
        if (lane < deg) {
            s = adj[off + lane];
            float t = ss1[s] + sdn;
            e = t > 0.f ? t : NEG * t;
        }
        float m = e;
#pragma unroll
        for (int o = 32; o; o >>= 1) m = fmaxf(m, __shfl_xor(m, o));
        float p = (lane < deg) ? __expf(e - m) : 0.f;
        float ds = p;
#pragma unroll
        for (int o = 32; o; o >>= 1) ds += __shfl_xor(ds, o);
        float w = p * (1.0f / ds);
        lw[wid][lane] = w;
        lsrc[wid][lane] = s;
        // gather: 8 subgroups x 8 lanes; each lane covers 8 bf16 features (16B uint4),
        // 2-way unroll -> up to 16 independent 128B rows in flight per wave.
        int g = lane >> 3, c = lane & 7;
        float a0[8] = {0,0,0,0,0,0,0,0};
        float a1[8] = {0,0,0,0,0,0,0,0};
        for (int tb = 0; tb < deg; tb += 16) {
            int t0 = tb + g, t1 = tb + g + 8;
            if (t0 < deg) {
                float w0 = lw[wid][t0];
                const uint4 v = *(const uint4*)(h1b + (size_t)lsrc[wid][t0] * HID + (c << 3));
                a0[0] += w0 * BFLO(v.x); a0[1] += w0 * BFHI(v.x);
                a0[2] += w0 * BFLO(v.y); a0[3] += w0 * BFHI(v.y);
                a0[4] += w0 * BFLO(v.z); a0[5] += w0 * BFHI(v.z);
                a0[6] += w0 * BFLO(v.w); a0[7] += w0 * BFHI(v.w);
            }
            if (t1 < deg) {
                float w1 = lw[wid][t1];
                const uint4 v = *(const uint4*)(h1b + (size_t)lsrc[wid][t1] * HID + (c << 3));
                a1[0] += w1 * BFLO(v.x); a1[1] += w1 * BFHI(v.x);
                a1[2] += w1 * BFLO(v.y); a1[3] += w1 * BFHI(v.y);
                a1[4] += w1 * BFLO(v.z); a1[5] += w1 * BFHI(v.z);
                a1[6] += w1 * BFLO(v.w); a1[7] += w1 * BFHI(v.w);
            }
        }
#pragma unroll
        for (int k = 0; k < 8; ++k) a0[k] += a1[k];
        // sum across the 8 subgroups (lanes c, c+8, ..., c+56)
#pragma unroll
        for (int o = 8; o <= 32; o <<= 1) {
#pragma unroll
            for (int k = 0; k < 8; ++k) a0[k] += __shfl_xor(a0[k], o);
        }
        // epilogue: +b1, ReLU, dot with W2 (8 features per lane)
        const float4 bA = *(const float4*)(b1 + (c << 3));
        const float4 bB = *(const float4*)(b1 + (c << 3) + 4);
        const float4 WA = *(const float4*)(W2 + (c << 3));
        const float4 WB = *(const float4*)(W2 + (c << 3) + 4);
        float p2 = fmaxf(a0[0] + bA.x, 0.f) * WA.x
                 + fmaxf(a0[1] + bA.y, 0.f) * WA.y
                 + fmaxf(a0[2] + bA.z, 0.f) * WA.z
                 + fmaxf(a0[3] + bA.w, 0.f) * WA.w
                 + fmaxf(a0[4] + bB.x, 0.f) * WB.x
                 + fmaxf(a0[5] + bB.y, 0.f) * WB.y
                 + fmaxf(a0[6] + bB.z, 0.f) * WB.z
                 + fmaxf(a0[7] + bB.w, 0.f) * WB.w;
#pragma unroll
        for (int o = 1; o <= 4; o <<= 1) p2 += __shfl_xor(p2, o);
        if (lane == 0) h2[n] = p2;
    } else {
        // ---- generic chunked 3-pass path (rare) ----
        float acc = 0.f;
        float m = -1e30f;
        for (int j0 = 0; j0 < deg; j0 += 64) {
            int j = j0 + lane;
            if (j < deg) {
                int s = adj[off + j];
                float e = ss1[s] + sdn;
                e = e > 0.f ? e : NEG * e;
                m = fmaxf(m, e);
            }
        }
#pragma unroll
        for (int o = 32; o; o >>= 1) m = fmaxf(m, __shfl_xor(m, o));
        float dsum = 0.f;
        for (int j0 = 0; j0 < deg; j0 += 64) {
            int j = j0 + lane;
            if (j < deg) {
                int s = adj[off + j];
                float e = ss1[s] + sdn;
                e = e > 0.f ? e : NEG * e;
                dsum += __expf(e - m);
            }
        }
#pragma unroll
        for (int o = 32; o; o >>= 1) dsum += __shfl_xor(dsum, o);
        float inv = 1.0f / dsum;
        for (int j0 = 0; j0 < deg; j0 += 64) {
            int j = j0 + lane;
            float w = 0.f; int s = 0;
            if (j < deg) {
                s = adj[off + j];
                float e = ss1[s] + sdn;
                e = e > 0.f ? e : NEG * e;
                w = __expf(e - m) * inv;
            }
            int lim = deg - j0; if (lim > 64) lim = 64;
            for (int t = 0; t < lim; ++t) {
                float cc = __shfl(w, t);
                int  sj = __shfl(s, t);
                acc += cc * BF(h1b[(size_t)sj * HID + lane]);
            }
        }
        float v = acc + b1[lane];
        v = fmaxf(v, 0.f);
        float p2 = v * W2[lane];
#pragma unroll
        for (int o = 32; o; o >>= 1) p2 += __shfl_xor(p2, o);
        if (lane == 0) h2[n] = p2;
    }
}

// ---------------- layer 2 softmax-aggregate (scalar features, single pass) ----------------
__global__ __launch_bounds__(256) void k_agg2(const int* __restrict__ rowptr,
                                              const int* __restrict__ cntd,
                                              const int* __restrict__ adj,
                                              const float* __restrict__ h2,
                                              const float* __restrict__ as2,
                                              const float* __restrict__ ad2,
                                              const float* __restrict__ b2,
                                              float* __restrict__ out) {
    int wid  = threadIdx.x >> 6;
    int lane = threadIdx.x & 63;
    int n = blockIdx.x * 4 + wid;
    if (n >= NN) return;
    int off = rowptr[n], deg = cntd[n];
    float as2v = as2[0];
    float sdn = h2[n] * ad2[0];

    if (deg <= 64) {
        float hv = 0.f, e = -1e30f;
        if (lane < deg) {
            int s = adj[off + lane];
            hv = h2[s];
            float t = hv * as2v + sdn;
            e = t > 0.f ? t : NEG * t;
        }
        float m = e;
#pragma unroll
        for (int o = 32; o; o >>= 1) m = fmaxf(m, __shfl_xor(m, o));
        float p = (lane < deg) ? __expf(e - m) : 0.f;
        float ds = p, ns = p * hv;
#pragma unroll
        for (int o = 32; o; o >>= 1) { ds += __shfl_xor(ds, o); ns += __shfl_xor(ns, o); }
        if (lane == 0) out[n] = ns / ds + b2[0];
    } else {
        float m = -1e30f;
        for (int j0 = 0; j0 < deg; j0 += 64) {
            int j = j0 + lane;
            if (j < deg) {
                int s = adj[off + j];
                float e = h2[s] * as2v + sdn;
                e = e > 0.f ? e : NEG * e;
                m = fmaxf(m, e);
            }
        }
#pragma unroll
        for (int o = 32; o; o >>= 1) m = fmaxf(m, __shfl_xor(m, o));
        float dsum = 0.f, nsum = 0.f;
        for (int j0 = 0; j0 < deg; j0 += 64) {
            int j = j0 + lane;
            if (j < deg) {
                int s = adj[off + j];
                float hv = h2[s];
                float e = hv * as2v + sdn;
                e = e > 0.f ? e : NEG * e;
                float ex = __expf(e - m);
                dsum += ex;
                nsum += ex * hv;
            }
        }
#pragma unroll
        for (int o = 32; o; o >>= 1) { dsum += __shfl_xor(dsum, o); nsum += __shfl_xor(nsum, o); }
        if (lane == 0) out[n] = nsum / dsum + b2[0];
    }
}

extern "C" void kernel_launch(void* const* d_in, const int* in_sizes, int n_in,
                              void* d_out, int out_size, void* d_ws, size_t ws_size,
                              hipStream_t stream) {
    const float* x      = (const float*)d_in[0];
    const int*   ei     = (const int*)d_in[1];
    const float* W1     = (const float*)d_in[2];
    const float* a_src1 = (const float*)d_in[3];
    const float* a_dst1 = (const float*)d_in[4];
    const float* b1     = (const float*)d_in[5];
    const float* W2     = (const float*)d_in[6];
    const float* as2    = (const float*)d_in[7];
    const float* ad2    = (const float*)d_in[8];
    const float* b2     = (const float*)d_in[9];
    float* out = (float*)d_out;

    // workspace layout
    ushort_t* h1b = (ushort_t*)d_ws;                    // N*64 bf16 = 12.8MB
    float* ss1  = (float*)(h1b + (size_t)NN * HID);     // N
    float* sd1  = ss1 + NN;                             // N
    float* h2   = sd1 + NN;                             // N
    int* rowptr = (int*)(h2 + NN);                      // N
    int* cntd   = rowptr + NN;                          // N
    int* bcur   = cntd + NN;                            // 1024
    unsigned* pairs = (unsigned*)(bcur + 1024);         // NBUK*BUKCAP (reused as adj)
    int* adj    = (int*)pairs;

    const int NSCT = (ET + SCT_TILE - 1) / SCT_TILE;    // 416

    hipMemsetAsync(bcur, 0, 1024 * sizeof(int), stream);

    k_proj<<<(NN + 3) / 4, 256, 0, stream>>>(x, W1, a_src1, a_dst1, h1b, ss1, sd1);
    k_bscatter<<<NSCT, 256, 0, stream>>>(ei, bcur, pairs);
    k_bsort<<<NBUK, 256, 0, stream>>>(bcur, pairs, rowptr, cntd);
    k_agg1<<<(NN + 3) / 4, 256, 0, stream>>>(rowptr, cntd, adj, ss1, sd1, h1b, b1, W2, h2);
    k_agg2<<<(NN + 3) / 4, 256, 0, stream>>>(rowptr, cntd, adj, h2, as2, ad2, b2, out);
}

// Round 6
// 123.124 us; speedup vs baseline: 1.4391x; 1.1603x over previous
//
#include <hip/hip_runtime.h>
#include <hip/hip_bf16.h>

#define NN 100000
#define EE 1600000
#define ET (EE + NN)            // edges incl. self loops
#define HID 64
#define NEG 0.2f
#define NBUK 782                // ceil(NN/128) buckets of 128 dst nodes
#define SCT_TILE 4096           // edges per block in scatter phase
#define BUKCAP 4096             // padded per-bucket capacity (mean 2176, sigma~47)
#define SH_CAP 4096

typedef unsigned short ushort_t;
#define BF(u)   __uint_as_float((unsigned)(u) << 16)
#define BFLO(u) __uint_as_float((unsigned)(u) << 16)
#define BFHI(u) __uint_as_float((unsigned)(u) & 0xFFFF0000u)

// ---------------- kernel 0: h1 = x@W1 (bf16), ss1 = h1.a_src1, sd1 = h1.a_dst1 ----------------
__global__ __launch_bounds__(256) void k_proj(const float* __restrict__ x,
                                              const float* __restrict__ W1,
                                              const float* __restrict__ a_src1,
                                              const float* __restrict__ a_dst1,
                                              ushort_t* __restrict__ h1b,
                                              float* __restrict__ ss1,
                                              float* __restrict__ sd1) {
    int wid  = threadIdx.x >> 6;
    int lane = threadIdx.x & 63;
    int n = blockIdx.x * 4 + wid;
    if (n >= NN) return;
    float h = 0.f;
#pragma unroll
    for (int k = 0; k < 5; ++k) h += x[n * 5 + k] * W1[k * HID + lane];
    unsigned u = __float_as_uint(h);
    unsigned r = (u + 0x7FFFu + ((u >> 16) & 1u)) >> 16;   // RNE bf16
    h1b[(size_t)n * HID + lane] = (ushort_t)r;
    float hq = BF(r);                 // scores from QUANTIZED h for consistency
    float a = hq * a_src1[lane];
    float b = hq * a_dst1[lane];
#pragma unroll
    for (int o = 32; o; o >>= 1) { a += __shfl_xor(a, o); b += __shfl_xor(b, o); }
    if (lane == 0) { ss1[n] = a; sd1[n] = b; }
}

// ---------------- CSR build ----------------
__global__ __launch_bounds__(256) void k_bscatter(const int* __restrict__ ei,
                                                  int* __restrict__ bcur,
                                                  unsigned* __restrict__ pairs) {
    __shared__ unsigned sp[SCT_TILE];
    __shared__ unsigned ga[SCT_TILE];
    __shared__ int h[NBUK], loc[NBUK], cur[NBUK];
    __shared__ int wsum[4];
    int tid = threadIdx.x;
    int wid = tid >> 6, lane = tid & 63;
    int base = blockIdx.x * SCT_TILE;
    int tilecnt = ET - base; if (tilecnt > SCT_TILE) tilecnt = SCT_TILE;

    for (int i = tid; i < NBUK; i += 256) h[i] = 0;
    __syncthreads();
    int sreg[SCT_TILE / 256], dreg[SCT_TILE / 256];
#pragma unroll
    for (int it = 0; it < SCT_TILE / 256; ++it) {
        int i = base + it * 256 + tid;
        if (i < ET) {
            int s, d;
            if (i < EE) { s = ei[i]; d = ei[EE + i]; }
            else        { s = i - EE; d = s; }
            sreg[it] = s; dreg[it] = d;
            atomicAdd(&h[d >> 7], 1);
        } else dreg[it] = -1;
    }
    __syncthreads();
    int b0 = tid * 4;
    int s0 = 0;
    if (b0 < NBUK)
        for (int k = 0; k < 4 && b0 + k < NBUK; ++k) s0 += h[b0 + k];
    int incl = s0;
#pragma unroll
    for (int o = 1; o < 64; o <<= 1) {
        int t = __shfl(incl, (lane - o) & 63);
        if (lane >= o) incl += t;
    }
    if (lane == 63) wsum[wid] = incl;
    __syncthreads();
    int wpref = 0;
    for (int w = 0; w < wid; ++w) wpref += wsum[w];
    if (b0 < NBUK) {
        int run = wpref + incl - s0;
        for (int k = 0; k < 4 && b0 + k < NBUK; ++k) {
            loc[b0 + k] = run;
            run += h[b0 + k];
        }
    }
    __syncthreads();
    for (int i = tid; i < NBUK; i += 256) {
        int c = h[i];
        cur[i] = c ? (atomicAdd(&bcur[i], c) + i * BUKCAP - loc[i]) : 0;
    }
    __syncthreads();
#pragma unroll
    for (int it = 0; it < SCT_TILE / 256; ++it) {
        if (dreg[it] >= 0) {
            int s = sreg[it], d = dreg[it];
            int b = d >> 7;
            unsigned pk = ((unsigned)(d & 127) << 17) | (unsigned)s;
            int pos = atomicAdd(&loc[b], 1);
            sp[pos] = pk;
            ga[pos] = (unsigned)(cur[b] + pos);
        }
    }
    __syncthreads();
    for (int i = tid; i < tilecnt; i += 256)
        pairs[ga[i]] = sp[i];
}

__global__ __launch_bounds__(256) void k_bsort(const int* __restrict__ bcur,
                                               unsigned* __restrict__ pairs,
                                               int* __restrict__ rowptr,
                                               int* __restrict__ cntd) {
    __shared__ unsigned sp[SH_CAP];
    __shared__ int hist[128], sc[128], cur2[128];
    int b = blockIdx.x;
    int cnt = bcur[b];
    if (cnt > SH_CAP) cnt = SH_CAP;
    int base = b * BUKCAP;
    int tid = threadIdx.x;
    if (tid < 128) hist[tid] = 0;
    __syncthreads();
    for (int i = tid; i < cnt; i += 256) {
        unsigned p = pairs[base + i];
        sp[i] = p;
        atomicAdd(&hist[p >> 17], 1);
    }
    __syncthreads();
    if (tid < 64) {
        int v0 = hist[2 * tid], v1 = hist[2 * tid + 1];
        int s = v0 + v1;
#pragma unroll
        for (int o = 1; o < 64; o <<= 1) {
            int t = __shfl(s, (tid - o) & 63);
            if (tid >= o) s += t;
        }
        int excl = s - v0 - v1;
        sc[2 * tid] = excl;
        sc[2 * tid + 1] = excl + v0;
    }
    __syncthreads();
    int nbase = b << 7;
    if (tid < 128 && nbase + tid < NN) {
        rowptr[nbase + tid] = base + sc[tid];
        cntd[nbase + tid]   = hist[tid];
        cur2[tid] = sc[tid];
    }
    __syncthreads();
    int* adj = (int*)pairs;
    for (int i = tid; i < cnt; i += 256) {
        unsigned p = sp[i];
        int ld = p >> 17;
        int pos = atomicAdd(&cur2[ld], 1);
        adj[base + pos] = (int)(p & 0x1FFFF);
    }
}

// ---------------- layer 1: full-wave single-node path (deg>32 fallback) ----------------
__device__ __forceinline__ void agg1_node(int n, int lane, int wid,
                                          float (*lw)[64], int (*lsrc)[64],
                                          const int* __restrict__ rowptr,
                                          const int* __restrict__ cntd,
                                          const int* __restrict__ adj,
                                          const float* __restrict__ ss1,
                                          const float* __restrict__ sd1,
                                          const ushort_t* __restrict__ h1b,
                                          const float* __restrict__ b1,
                                          const float* __restrict__ W2,
                                          float* __restrict__ h2) {
    int off = rowptr[n], deg = cntd[n];
    float sdn = sd1[n];
    if (deg <= 64) {
        int s = 0; float e = -1e30f;
        if (lane < deg) {
            s = adj[off + lane];
            float t = ss1[s] + sdn;
            e = t > 0.f ? t : NEG * t;
        }
        float m = e;
#pragma unroll
        for (int o = 32; o; o >>= 1) m = fmaxf(m, __shfl_xor(m, o));
        float p = (lane < deg) ? __expf(e - m) : 0.f;
        float ds = p;
#pragma unroll
        for (int o = 32; o; o >>= 1) ds += __shfl_xor(ds, o);
        float w = p * (1.0f / ds);
        lw[wid][lane] = w;
        lsrc[wid][lane] = s;
        int g = lane >> 3, c = lane & 7;
        float a0[8] = {0,0,0,0,0,0,0,0};
        float a1[8] = {0,0,0,0,0,0,0,0};
        for (int tb = 0; tb < deg; tb += 16) {
            int t0 = tb + g, t1 = tb + g + 8;
            if (t0 < deg) {
                float w0 = lw[wid][t0];
                const uint4 v = *(const uint4*)(h1b + (size_t)lsrc[wid][t0] * HID + (c << 3));
                a0[0] += w0 * BFLO(v.x); a0[1] += w0 * BFHI(v.x);
                a0[2] += w0 * BFLO(v.y); a0[3] += w0 * BFHI(v.y);
                a0[4] += w0 * BFLO(v.z); a0[5] += w0 * BFHI(v.z);
                a0[6] += w0 * BFLO(v.w); a0[7] += w0 * BFHI(v.w);
            }
            if (t1 < deg) {
                float w1 = lw[wid][t1];
                const uint4 v = *(const uint4*)(h1b + (size_t)lsrc[wid][t1] * HID + (c << 3));
                a1[0] += w1 * BFLO(v.x); a1[1] += w1 * BFHI(v.x);
                a1[2] += w1 * BFLO(v.y); a1[3] += w1 * BFHI(v.y);
                a1[4] += w1 * BFLO(v.z); a1[5] += w1 * BFHI(v.z);
                a1[6] += w1 * BFLO(v.w); a1[7] += w1 * BFHI(v.w);
            }
        }
#pragma unroll
        for (int k = 0; k < 8; ++k) a0[k] += a1[k];
#pragma unroll
        for (int o = 8; o <= 32; o <<= 1) {
#pragma unroll
            for (int k = 0; k < 8; ++k) a0[k] += __shfl_xor(a0[k], o);
        }
        const float4 bA = *(const float4*)(b1 + (c << 3));
        const float4 bB = *(const float4*)(b1 + (c << 3) + 4);
        const float4 WA = *(const float4*)(W2 + (c << 3));
        const float4 WB = *(const float4*)(W2 + (c << 3) + 4);
        float p2 = fmaxf(a0[0] + bA.x, 0.f) * WA.x + fmaxf(a0[1] + bA.y, 0.f) * WA.y
                 + fmaxf(a0[2] + bA.z, 0.f) * WA.z + fmaxf(a0[3] + bA.w, 0.f) * WA.w
                 + fmaxf(a0[4] + bB.x, 0.f) * WB.x + fmaxf(a0[5] + bB.y, 0.f) * WB.y
                 + fmaxf(a0[6] + bB.z, 0.f) * WB.z + fmaxf(a0[7] + bB.w, 0.f) * WB.w;
#pragma unroll
        for (int o = 1; o <= 4; o <<= 1) p2 += __shfl_xor(p2, o);
        if (lane == 0) h2[n] = p2;
    } else {
        float acc = 0.f;
        float m = -1e30f;
        for (int j0 = 0; j0 < deg; j0 += 64) {
            int j = j0 + lane;
            if (j < deg) {
                int s = adj[off + j];
                float e = ss1[s] + sdn;
                e = e > 0.f ? e : NEG * e;
                m = fmaxf(m, e);
            }
        }
#pragma unroll
        for (int o = 32; o; o >>= 1) m = fmaxf(m, __shfl_xor(m, o));
        float dsum = 0.f;
        for (int j0 = 0; j0 < deg; j0 += 64) {
            int j = j0 + lane;
            if (j < deg) {
                int s = adj[off + j];
                float e = ss1[s] + sdn;
                e = e > 0.f ? e : NEG * e;
                dsum += __expf(e - m);
            }
        }
#pragma unroll
        for (int o = 32; o; o >>= 1) dsum += __shfl_xor(dsum, o);
        float inv = 1.0f / dsum;
        for (int j0 = 0; j0 < deg; j0 += 64) {
            int j = j0 + lane;
            float w = 0.f; int s = 0;
            if (j < deg) {
                s = adj[off + j];
                float e = ss1[s] + sdn;
                e = e > 0.f ? e : NEG * e;
                w = __expf(e - m) * inv;
            }
            int lim = deg - j0; if (lim > 64) lim = 64;
            for (int t = 0; t < lim; ++t) {
                float cc = __shfl(w, t);
                int  sj = __shfl(s, t);
                acc += cc * BF(h1b[(size_t)sj * HID + lane]);
            }
        }
        float v = fmaxf(acc + b1[lane], 0.f);
        float p2 = v * W2[lane];
#pragma unroll
        for (int o = 32; o; o >>= 1) p2 += __shfl_xor(p2, o);
        if (lane == 0) h2[n] = p2;
    }
}

// ---------------- layer 1: 2 nodes per wave ----------------
__global__ __launch_bounds__(256) void k_agg1(const int* __restrict__ rowptr,
                                              const int* __restrict__ cntd,
                                              const int* __restrict__ adj,
                                              const float* __restrict__ ss1,
                                              const float* __restrict__ sd1,
                                              const ushort_t* __restrict__ h1b,
                                              const float* __restrict__ b1,
                                              const float* __restrict__ W2,
                                              float* __restrict__ h2) {
    __shared__ float lw[4][64];
    __shared__ int   lsrc[4][64];
    int wid  = threadIdx.x >> 6;
    int lane = threadIdx.x & 63;
    int n0 = (blockIdx.x * 4 + wid) * 2;
    if (n0 >= NN) return;
    int deg0 = cntd[n0], deg1 = cntd[n0 + 1];

    if (deg0 <= 32 && deg1 <= 32) {
        // ---- pair fast path: lanes 0-31 -> node n0, lanes 32-63 -> node n0+1 ----
        int half = lane >> 5, li = lane & 31;
        int nh = n0 + half;
        int off = rowptr[nh];
        int deg = half ? deg1 : deg0;
        float sdn = sd1[nh];
        int s = 0; float e = -1e30f;
        if (li < deg) {
            s = adj[off + li];
            float t = ss1[s] + sdn;
            e = t > 0.f ? t : NEG * t;
        }
        float m = e;
#pragma unroll
        for (int o = 1; o <= 16; o <<= 1) m = fmaxf(m, __shfl_xor(m, o));
        float p = (li < deg) ? __expf(e - m) : 0.f;
        float ds = p;
#pragma unroll
        for (int o = 1; o <= 16; o <<= 1) ds += __shfl_xor(ds, o);
        float w = p * (1.0f / ds);
        lw[wid][lane] = w;          // [half*32 + edge]
        lsrc[wid][lane] = s;
        // gather: per half, 4 subgroups x 8 lanes; 2-unroll -> 16 rows in flight/wave
        int g = (lane >> 3) & 3, c = lane & 7;
        int lbase = half << 5;
        float a0[8] = {0,0,0,0,0,0,0,0};
        float a1[8] = {0,0,0,0,0,0,0,0};
        int mdeg = deg0 > deg1 ? deg0 : deg1;
        for (int tb = 0; tb < mdeg; tb += 8) {
            int t0 = tb + g, t1 = tb + g + 4;
            if (t0 < deg) {
                float w0 = lw[wid][lbase + t0];
                const uint4 v = *(const uint4*)(h1b + (size_t)lsrc[wid][lbase + t0] * HID + (c << 3));
                a0[0] += w0 * BFLO(v.x); a0[1] += w0 * BFHI(v.x);
                a0[2] += w0 * BFLO(v.y); a0[3] += w0 * BFHI(v.y);
                a0[4] += w0 * BFLO(v.z); a0[5] += w0 * BFHI(v.z);
                a0[6] += w0 * BFLO(v.w); a0[7] += w0 * BFHI(v.w);
            }
            if (t1 < deg) {
                float w1 = lw[wid][lbase + t1];
                const uint4 v = *(const uint4*)(h1b + (size_t)lsrc[wid][lbase + t1] * HID + (c << 3));
                a1[0] += w1 * BFLO(v.x); a1[1] += w1 * BFHI(v.x);
                a1[2] += w1 * BFLO(v.y); a1[3] += w1 * BFHI(v.y);
                a1[4] += w1 * BFLO(v.z); a1[5] += w1 * BFHI(v.z);
                a1[6] += w1 * BFLO(v.w); a1[7] += w1 * BFHI(v.w);
            }
        }
#pragma unroll
        for (int k = 0; k < 8; ++k) a0[k] += a1[k];
        // reduce over the 4 subgroups within each half
#pragma unroll
        for (int o = 8; o <= 16; o <<= 1) {
#pragma unroll
            for (int k = 0; k < 8; ++k) a0[k] += __shfl_xor(a0[k], o);
        }
        const float4 bA = *(const float4*)(b1 + (c << 3));
        const float4 bB = *(const float4*)(b1 + (c << 3) + 4);
        const float4 WA = *(const float4*)(W2 + (c << 3));
        const float4 WB = *(const float4*)(W2 + (c << 3) + 4);
        float p2 = fmaxf(a0[0] + bA.x, 0.f) * WA.x + fmaxf(a0[1] + bA.y, 0.f) * WA.y
                 + fmaxf(a0[2] + bA.z, 0.f) * WA.z + fmaxf(a0[3] + bA.w, 0.f) * WA.w
                 + fmaxf(a0[4] + bB.x, 0.f) * WB.x + fmaxf(a0[5] + bB.y, 0.f) * WB.y
                 + fmaxf(a0[6] + bB.z, 0.f) * WB.z + fmaxf(a0[7] + bB.w, 0.f) * WB.w;
#pragma unroll
        for (int o = 1; o <= 4; o <<= 1) p2 += __shfl_xor(p2, o);
        if (li == 0) h2[nh] = p2;
    } else {
        agg1_node(n0,     lane, wid, lw, lsrc, rowptr, cntd, adj, ss1, sd1, h1b, b1, W2, h2);
        agg1_node(n0 + 1, lane, wid, lw, lsrc, rowptr, cntd, adj, ss1, sd1, h1b, b1, W2, h2);
    }
}

// ---------------- layer 2: full-wave single-node fallback ----------------
__device__ __forceinline__ void agg2_node(int n, int lane,
                                          const int* __restrict__ rowptr,
                                          const int* __restrict__ cntd,
                                          const int* __restrict__ adj,
                                          const float* __restrict__ h2,
                                          float as2v, float ad2v, float b2v,
                                          float* __restrict__ out) {
    int off = rowptr[n], deg = cntd[n];
    float sdn = h2[n] * ad2v;
    float m = -1e30f;
    for (int j0 = 0; j0 < deg; j0 += 64) {
        int j = j0 + lane;
        if (j < deg) {
            int s = adj[off + j];
            float e = h2[s] * as2v + sdn;
            e = e > 0.f ? e : NEG * e;
            m = fmaxf(m, e);
        }
    }
#pragma unroll
    for (int o = 32; o; o >>= 1) m = fmaxf(m, __shfl_xor(m, o));
    float dsum = 0.f, nsum = 0.f;
    for (int j0 = 0; j0 < deg; j0 += 64) {
        int j = j0 + lane;
        if (j < deg) {
            int s = adj[off + j];
            float hv = h2[s];
            float e = hv * as2v + sdn;
            e = e > 0.f ? e : NEG * e;
            float ex = __expf(e - m);
            dsum += ex;
            nsum += ex * hv;
        }
    }
#pragma unroll
    for (int o = 32; o; o >>= 1) { dsum += __shfl_xor(dsum, o); nsum += __shfl_xor(nsum, o); }
    if (lane == 0) out[n] = nsum / dsum + b2v;
}

// ---------------- layer 2: 2 nodes per wave ----------------
__global__ __launch_bounds__(256) void k_agg2(const int* __restrict__ rowptr,
                                              const int* __restrict__ cntd,
                                              const int* __restrict__ adj,
                                              const float* __restrict__ h2,
                                              const float* __restrict__ as2,
                                              const float* __restrict__ ad2,
                                              const float* __restrict__ b2,
                                              float* __restrict__ out) {
    int wid  = threadIdx.x >> 6;
    int lane = threadIdx.x & 63;
    int n0 = (blockIdx.x * 4 + wid) * 2;
    if (n0 >= NN) return;
    float as2v = as2[0], ad2v = ad2[0], b2v = b2[0];
    int deg0 = cntd[n0], deg1 = cntd[n0 + 1];

    if (deg0 <= 32 && deg1 <= 32) {
        int half = lane >> 5, li = lane & 31;
        int nh = n0 + half;
        int off = rowptr[nh];
        int deg = half ? deg1 : deg0;
        float sdn = h2[nh] * ad2v;
        float hv = 0.f, e = -1e30f;
        if (li < deg) {
            int s = adj[off + li];
            hv = h2[s];
            float t = hv * as2v + sdn;
            e = t > 0.f ? t : NEG * t;
        }
        float m = e;
#pragma unroll
        for (int o = 1; o <= 16; o <<= 1) m = fmaxf(m, __shfl_xor(m, o));
        float p = (li < deg) ? __expf(e - m) : 0.f;
        float ds = p, ns = p * hv;
#pragma unroll
        for (int o = 1; o <= 16; o <<= 1) { ds += __shfl_xor(ds, o); ns += __shfl_xor(ns, o); }
        if (li == 0) out[nh] = ns / ds + b2v;
    } else {
        agg2_node(n0,     lane, rowptr, cntd, adj, h2, as2v, ad2v, b2v, out);
        agg2_node(n0 + 1, lane, rowptr, cntd, adj, h2, as2v, ad2v, b2v, out);
    }
}

extern "C" void kernel_launch(void* const* d_in, const int* in_sizes, int n_in,
                              void* d_out, int out_size, void* d_ws, size_t ws_size,
                              hipStream_t stream) {
    const float* x      = (const float*)d_in[0];
    const int*   ei     = (const int*)d_in[1];
    const float* W1     = (const float*)d_in[2];
    const float* a_src1 = (const float*)d_in[3];
    const float* a_dst1 = (const float*)d_in[4];
    const float* b1     = (const float*)d_in[5];
    const float* W2     = (const float*)d_in[6];
    const float* as2    = (const float*)d_in[7];
    const float* ad2    = (const float*)d_in[8];
    const float* b2     = (const float*)d_in[9];
    float* out = (float*)d_out;

    // workspace layout
    ushort_t* h1b = (ushort_t*)d_ws;                    // N*64 bf16 = 12.8MB
    float* ss1  = (float*)(h1b + (size_t)NN * HID);     // N
    float* sd1  = ss1 + NN;                             // N
    float* h2   = sd1 + NN;                             // N
    int* rowptr = (int*)(h2 + NN);                      // N
    int* cntd   = rowptr + NN;                          // N
    int* bcur   = cntd + NN;                            // 1024
    unsigned* pairs = (unsigned*)(bcur + 1024);         // NBUK*BUKCAP (reused as adj)
    int* adj    = (int*)pairs;

    const int NSCT = (ET + SCT_TILE - 1) / SCT_TILE;    // 416
    const int NPAIR = (NN / 2 + 3) / 4;                 // 12500 blocks, 2 nodes/wave

    hipMemsetAsync(bcur, 0, 1024 * sizeof(int), stream);

    k_proj<<<(NN + 3) / 4, 256, 0, stream>>>(x, W1, a_src1, a_dst1, h1b, ss1, sd1);
    k_bscatter<<<NSCT, 256, 0, stream>>>(ei, bcur, pairs);
    k_bsort<<<NBUK, 256, 0, stream>>>(bcur, pairs, rowptr, cntd);
    k_agg1<<<NPAIR, 256, 0, stream>>>(rowptr, cntd, adj, ss1, sd1, h1b, b1, W2, h2);
    k_agg2<<<NPAIR, 256, 0, stream>>>(rowptr, cntd, adj, h2, as2, ad2, b2, out);
}